// Round 4
// baseline (287.287 us; speedup 1.0000x reference)
//
#include <hip/hip_runtime.h>
#include <hip/hip_bf16.h>

typedef unsigned short u16_t;
typedef unsigned int   u32_t;

#define B_ROWS  16384
#define D_IN    1024
#define D_OUT   512
#define NEXP    16
#define CNT_STRIDE 16   // pad each expert counter to its own 64B line (R2 post-mortem)
#define EPSF    2.2204460492503131e-16f

using short8  = __attribute__((ext_vector_type(8))) short;
using floatx4 = __attribute__((ext_vector_type(4))) float;

// async global->LDS, 16B per lane; LDS dest = wave-uniform base + lane*16
#define GLDS16(gp, lp) __builtin_amdgcn_global_load_lds( \
    (const __attribute__((address_space(1))) void*)(gp), \
    (__attribute__((address_space(3))) void*)(lp), 16, 0, 0)

__device__ __forceinline__ u16_t f2bf(float f) {
    u32_t u = __float_as_uint(f);
    u += 0x7fffu + ((u >> 16) & 1u);        // round-to-nearest-even
    return (u16_t)(u >> 16);
}

// ---------------------------------------------------------------------------
// Transpose w_router [D_IN][E] -> wrT [E][D_IN] f32 (64 KB).
// ---------------------------------------------------------------------------
__global__ __launch_bounds__(256) void transpose_wr(
        const float* __restrict__ wr, float* __restrict__ wrT) {
    int i = blockIdx.x * 256 + threadIdx.x;      // i = e*D_IN + d
    int e = i >> 10, d = i & 1023;
    wrT[i] = wr[d * NEXP + e];
}

// ---------------------------------------------------------------------------
// x f32 -> bf16 (row-major unchanged). 8 elems/thread.
// ---------------------------------------------------------------------------
__global__ __launch_bounds__(256) void convert_x(
        const float* __restrict__ x, u16_t* __restrict__ xb) {
    size_t i = ((size_t)blockIdx.x * 256 + threadIdx.x) * 8;
    float4 a = *(const float4*)(x + i);
    float4 b = *(const float4*)(x + i + 4);
    union { u16_t us[8]; uint4 v; } p;
    p.us[0] = f2bf(a.x); p.us[1] = f2bf(a.y); p.us[2] = f2bf(a.z); p.us[3] = f2bf(a.w);
    p.us[4] = f2bf(b.x); p.us[5] = f2bf(b.y); p.us[6] = f2bf(b.z); p.us[7] = f2bf(b.w);
    *(uint4*)(xb + i) = p.v;
}

// ---------------------------------------------------------------------------
// w_experts [e][k][n] f32 -> wT [e][n][k] bf16 via LDS tile (R3 post-mortem:
// old version's 2KB-strided 16B stores were fully uncoalesced).
// Block = (kblk, nblk, e): tile 128k x 64n. Loads coalesced over n; stores
// coalesced over k (4 lanes x 64B = 256B contiguous per n-row).
// ---------------------------------------------------------------------------
__global__ __launch_bounds__(256) void convert_wT(
        const float* __restrict__ w, u16_t* __restrict__ wT) {
    __shared__ u16_t sh[128][72];               // pad 64->72
    int e = blockIdx.z, k0 = blockIdx.x * 128, n0 = blockIdx.y * 64;
    int t = threadIdx.x;
    int kk = t >> 4, nc = (t & 15) * 4;
    const float* src = w + ((size_t)e * D_IN + k0 + kk) * D_OUT + n0 + nc;
    #pragma unroll
    for (int p = 0; p < 8; ++p) {
        float4 v = *(const float4*)(src + (size_t)p * 16 * D_OUT);
        sh[p * 16 + kk][nc + 0] = f2bf(v.x);
        sh[p * 16 + kk][nc + 1] = f2bf(v.y);
        sh[p * 16 + kk][nc + 2] = f2bf(v.z);
        sh[p * 16 + kk][nc + 3] = f2bf(v.w);
    }
    __syncthreads();
    int nn = t >> 2, c = t & 3;                 // 4 threads per n-row, 64B each
    u16_t* dst = wT + ((size_t)e * D_OUT + n0 + nn) * D_IN + k0 + c * 32;
    #pragma unroll
    for (int j = 0; j < 4; ++j) {
        union { u16_t us[8]; uint4 v; } p;
        #pragma unroll
        for (int jj = 0; jj < 8; ++jj) p.us[jj] = sh[c * 32 + j * 8 + jj][nn];
        *(uint4*)(dst + j * 8) = p.v;
    }
}

// ---------------------------------------------------------------------------
// Router v4: 32 rows/block, thread=(row lr=t>>3, oct q=t&7), wrT in LDS.
// q-minor chunking d=i*32+q*4: 8 q-lanes span all 32 banks once ->
// conflict-free (R3: q*128 stride was ==0 mod 32 -> 4-way conflicts).
// f64 dots (exact top-2 vs np ref); hierarchical atomics (R2 fix).
// ---------------------------------------------------------------------------
__global__ __launch_bounds__(256) void router_kernel(
        const float* __restrict__ x, const float* __restrict__ wrT,
        int* __restrict__ counts, int* __restrict__ rowlist,
        float* __restrict__ gatelist) {
    __shared__ float wsh[NEXP * D_IN];          // 64 KB [e][d]
    __shared__ int hist[NEXP], base[NEXP], hist2[NEXP];
    __shared__ unsigned char eidx_sh[32][2];
    __shared__ float g_sh[32][2];

    int t = threadIdx.x;
    {   // stage wrT: 16384 floats / 256 threads = 16 float4 each
        const float4* src = (const float4*)wrT;
        float4* dst = (float4*)wsh;
        #pragma unroll
        for (int i = 0; i < 16; ++i) dst[t + 256 * i] = src[t + 256 * i];
    }
    if (t < NEXP) { hist[t] = 0; hist2[t] = 0; }
    __syncthreads();

    int lr = t >> 3, q = t & 7;
    int row = blockIdx.x * 32 + lr;
    const float4* xq = (const float4*)(x + (size_t)row * D_IN);

    double acc[NEXP];
    #pragma unroll
    for (int e = 0; e < NEXP; ++e) acc[e] = 0.0;

    for (int i = 0; i < 32; ++i) {
        float4 xv = xq[i * 8 + q];              // d = i*32 + q*4
        double x0 = xv.x, x1 = xv.y, x2 = xv.z, x3 = xv.w;
        #pragma unroll
        for (int e = 0; e < NEXP; ++e) {
            float4 wv = *(const float4*)(&wsh[e * D_IN + i * 32 + q * 4]);
            acc[e] += x0 * (double)wv.x;
            acc[e] += x1 * (double)wv.y;
            acc[e] += x2 * (double)wv.z;
            acc[e] += x3 * (double)wv.w;
        }
    }
    #pragma unroll
    for (int e = 0; e < NEXP; ++e) {
        acc[e] += __shfl_xor(acc[e], 1);
        acc[e] += __shfl_xor(acc[e], 2);
        acc[e] += __shfl_xor(acc[e], 4);
    }
    if (q == 0) {
        // top-2, stable (lower index wins ties) == jax.lax.top_k
        int i1 = 0; double v1 = acc[0];
        #pragma unroll
        for (int e = 1; e < NEXP; ++e) if (acc[e] > v1) { v1 = acc[e]; i1 = e; }
        int i2 = -1; double v2 = -1.0e300;
        #pragma unroll
        for (int e = 0; e < NEXP; ++e) if (e != i1 && acc[e] > v2) { v2 = acc[e]; i2 = e; }
        double ed = exp(v2 - v1);               // <= 1
        double s = 1.0 + ed;
        eidx_sh[lr][0] = (unsigned char)i1; g_sh[lr][0] = (float)(1.0 / s);
        eidx_sh[lr][1] = (unsigned char)i2; g_sh[lr][1] = (float)(ed / s);
        atomicAdd(&hist[i1], 1);
        atomicAdd(&hist[i2], 1);
    }
    __syncthreads();
    if (t < NEXP) base[t] = atomicAdd(&counts[t * CNT_STRIDE], hist[t]);
    __syncthreads();
    if (t < 64) {
        int r = t >> 1, sl = t & 1;
        int e = eidx_sh[r][sl];
        int pos = base[e] + atomicAdd(&hist2[e], 1);
        rowlist[e * B_ROWS + pos] = ((blockIdx.x * 32 + r) << 1) | sl;
        gatelist[e * B_ROWS + pos] = g_sh[r][sl];
    }
}

// ---------------------------------------------------------------------------
// Grouped expert GEMM v2 (R3 post-mortem: 8.6M LDS bank conflicts + no
// global_load_lds). Fragment-order LDS: A/B stored as [tile][q][lm] 16B
// chunks so lane i's ds_read_b128 is base+lane*16 (conflict-free, linear)
// and staging is 4 global_load_lds_dwordx4 per wave/iter (no VGPR round
// trip, no LDS write instructions, no pack VALU).
// 128x128 tile, BK=32, mfma 16x16x32 bf16, 2x2 waves.
// ---------------------------------------------------------------------------
template<bool USE_CONTRIB>
__global__ __launch_bounds__(256) void moe_gemm_bf16(
        const u16_t* __restrict__ xb, const u16_t* __restrict__ wT,
        const int* __restrict__ counts, const int* __restrict__ rowlist,
        const float* __restrict__ gatelist,
        float* __restrict__ out, float* __restrict__ contrib) {
    int e = blockIdx.z;
    int n_e = counts[e * CNT_STRIDE];
    int ty = blockIdx.y;
    if (ty * 128 >= n_e) return;
    int n0 = blockIdx.x * 128;

    // [mtile(8)][q(4)][lm(16)][j(8)] bf16 = 8 KB each
    __shared__ __align__(16) u16_t Af[8192];
    __shared__ __align__(16) u16_t Bf[8192];
    __shared__ int   rid_sh[128];
    __shared__ float gt_sh[128];

    int t = threadIdx.x;
    if (t < 128) {
        int gi = ty * 128 + t;
        int v = 0; float g = 0.f;
        if (gi < n_e) { v = rowlist[e * B_ROWS + gi]; g = gatelist[e * B_ROWS + gi]; }
        rid_sh[t] = v; gt_sh[t] = g;
    }
    __syncthreads();

    int lane = t & 63, wv = t >> 6;
    int wm = wv >> 1, wn = wv & 1;
    int lm = lane & 15, q = lane >> 4;

    // wave wv stages A mtiles {2wv,2wv+1} and B ntiles {2wv,2wv+1}
    int m0 = 2 * wv, m1 = 2 * wv + 1;
    const u16_t* aG0 = xb + (size_t)(rid_sh[m0 * 16 + lm] >> 1) * D_IN + q * 8;
    const u16_t* aG1 = xb + (size_t)(rid_sh[m1 * 16 + lm] >> 1) * D_IN + q * 8;
    const u16_t* bG0 = wT + ((size_t)e * D_OUT + n0 + m0 * 16 + lm) * D_IN + q * 8;
    const u16_t* bG1 = wT + ((size_t)e * D_OUT + n0 + m1 * 16 + lm) * D_IN + q * 8;
    u16_t* aL0 = Af + m0 * 512;   // lane lands at +lane*8 u16 = [q][lm] chunk
    u16_t* aL1 = Af + m1 * 512;
    u16_t* bL0 = Bf + m0 * 512;
    u16_t* bL1 = Bf + m1 * 512;

    floatx4 acc[4][4];
    #pragma unroll
    for (int mi = 0; mi < 4; ++mi)
        #pragma unroll
        for (int ni = 0; ni < 4; ++ni)
            acc[mi][ni] = (floatx4){0.f, 0.f, 0.f, 0.f};

    for (int it = 0; it < D_IN / 32; ++it) {
        __syncthreads();          // prev iter's fragment reads complete
        GLDS16(aG0, aL0);
        GLDS16(aG1, aL1);
        GLDS16(bG0, bL0);
        GLDS16(bG1, bL1);
        aG0 += 32; aG1 += 32; bG0 += 32; bG1 += 32;
        __syncthreads();          // vmcnt(0) drain: tiles resident

        short8 afr[4], bfr[4];
        #pragma unroll
        for (int mi = 0; mi < 4; ++mi)
            afr[mi] = *(const short8*)(Af + (wm * 4 + mi) * 512 + lane * 8);
        #pragma unroll
        for (int ni = 0; ni < 4; ++ni)
            bfr[ni] = *(const short8*)(Bf + (wn * 4 + ni) * 512 + lane * 8);
        #pragma unroll
        for (int mi = 0; mi < 4; ++mi)
            #pragma unroll
            for (int ni = 0; ni < 4; ++ni)
                acc[mi][ni] = __builtin_amdgcn_mfma_f32_16x16x32_bf16(
                    afr[mi], bfr[ni], acc[mi][ni], 0, 0, 0);
    }

    // epilogue: C/D layout col=lane&15, row=(lane>>4)*4+reg
    #pragma unroll
    for (int mi = 0; mi < 4; ++mi) {
        int rbase = wm * 64 + mi * 16 + q * 4;
        #pragma unroll
        for (int r = 0; r < 4; ++r) {
            int row = rbase + r;
            int gi = ty * 128 + row;
            bool ok = gi < n_e;
            int v = rid_sh[row];
            float g = gt_sh[row];
            size_t orow = (size_t)(v >> 1) * D_OUT;
            #pragma unroll
            for (int ni = 0; ni < 4; ++ni) {
                int c = n0 + wn * 64 + ni * 16 + lm;
                float val = g * __expf(acc[mi][ni][r]);
                if (ok) {
                    if (USE_CONTRIB) {
                        float* dst = (v & 1) ? contrib : out;
                        dst[orow + c] = val;
                    } else {
                        atomicAdd(&out[orow + c], val);
                    }
                }
            }
        }
    }
}

// ---------------------------------------------------------------------------
// Fallback f32-input GEMM (used only when ws too small for bf16 buffers).
// ---------------------------------------------------------------------------
template<bool USE_CONTRIB>
__global__ __launch_bounds__(256) void moe_gemm(
        const float* __restrict__ x, const float* __restrict__ w,
        const int* __restrict__ counts, const int* __restrict__ rowlist,
        const float* __restrict__ gatelist,
        float* __restrict__ out, float* __restrict__ contrib) {
    int e = blockIdx.z;
    int n_e = counts[e * CNT_STRIDE];
    int ty = blockIdx.y;
    if (ty * 128 >= n_e) return;
    int n0 = blockIdx.x * 128;

    __shared__ u16_t Ash[128][40];
    __shared__ u32_t Bsh[16][132];
    __shared__ int   rid_sh[128];
    __shared__ float gt_sh[128];

    int t = threadIdx.x;
    if (t < 128) {
        int gi = ty * 128 + t;
        int v = 0; float g = 0.f;
        if (gi < n_e) { v = rowlist[e * B_ROWS + gi]; g = gatelist[e * B_ROWS + gi]; }
        rid_sh[t] = v; gt_sh[t] = g;
    }
    __syncthreads();

    int ar = t >> 1, ah = t & 1;
    const float* xptr = x + (size_t)(rid_sh[ar] >> 1) * D_IN + ah * 16;
    int bkp = t >> 4, bng = t & 15;
    const float* wptr = w + (size_t)e * (D_IN * D_OUT)
                          + (size_t)(2 * bkp) * D_OUT + n0 + bng * 8;

    int lane = t & 63, wv = t >> 6;
    int wm = wv >> 1, wn = wv & 1;
    int lm = lane & 15, q = lane >> 4;

    floatx4 acc[4][4];
    #pragma unroll
    for (int mi = 0; mi < 4; ++mi)
        #pragma unroll
        for (int ni = 0; ni < 4; ++ni)
            acc[mi][ni] = (floatx4){0.f, 0.f, 0.f, 0.f};

    for (int it = 0; it < D_IN / 32; ++it) {
        float4 av0 = *(const float4*)(xptr + 0);
        float4 av1 = *(const float4*)(xptr + 4);
        float4 av2 = *(const float4*)(xptr + 8);
        float4 av3 = *(const float4*)(xptr + 12);
        xptr += 32;
        float4 b0 = *(const float4*)(wptr + 0);
        float4 b1 = *(const float4*)(wptr + 4);
        float4 b2 = *(const float4*)(wptr + D_OUT);
        float4 b3 = *(const float4*)(wptr + D_OUT + 4);
        wptr += 32 * D_OUT;

        __syncthreads();
        {
            union { u16_t us[16]; uint4 v[2]; } ap;
            float af[16] = {av0.x, av0.y, av0.z, av0.w, av1.x, av1.y, av1.z, av1.w,
                            av2.x, av2.y, av2.z, av2.w, av3.x, av3.y, av3.z, av3.w};
            #pragma unroll
            for (int j = 0; j < 16; ++j) ap.us[j] = f2bf(af[j]);
            *(uint4*)(&Ash[ar][ah * 16])     = ap.v[0];
            *(uint4*)(&Ash[ar][ah * 16 + 8]) = ap.v[1];
        }
        {
            union { u32_t up[8]; uint4 v[2]; } bp;
            bp.up[0] = (u32_t)f2bf(b0.x) | ((u32_t)f2bf(b2.x) << 16);
            bp.up[1] = (u32_t)f2bf(b0.y) | ((u32_t)f2bf(b2.y) << 16);
            bp.up[2] = (u32_t)f2bf(b0.z) | ((u32_t)f2bf(b2.z) << 16);
            bp.up[3] = (u32_t)f2bf(b0.w) | ((u32_t)f2bf(b2.w) << 16);
            bp.up[4] = (u32_t)f2bf(b1.x) | ((u32_t)f2bf(b3.x) << 16);
            bp.up[5] = (u32_t)f2bf(b1.y) | ((u32_t)f2bf(b3.y) << 16);
            bp.up[6] = (u32_t)f2bf(b1.z) | ((u32_t)f2bf(b3.z) << 16);
            bp.up[7] = (u32_t)f2bf(b1.w) | ((u32_t)f2bf(b3.w) << 16);
            *(uint4*)(&Bsh[bkp][bng * 8])     = bp.v[0];
            *(uint4*)(&Bsh[bkp][bng * 8 + 4]) = bp.v[1];
        }
        __syncthreads();

        short8 afr[4];
        #pragma unroll
        for (int mi = 0; mi < 4; ++mi)
            afr[mi] = *(const short8*)(&Ash[wm * 64 + mi * 16 + lm][q * 8]);
        short8 bfr[4];
        #pragma unroll
        for (int ni = 0; ni < 4; ++ni) {
            int nn = wn * 64 + ni * 16 + lm;
            union { uint4 u; short8 s; } cv;
            cv.u.x = Bsh[q * 4 + 0][nn];
            cv.u.y = Bsh[q * 4 + 1][nn];
            cv.u.z = Bsh[q * 4 + 2][nn];
            cv.u.w = Bsh[q * 4 + 3][nn];
            bfr[ni] = cv.s;
        }
        #pragma unroll
        for (int mi = 0; mi < 4; ++mi)
            #pragma unroll
            for (int ni = 0; ni < 4; ++ni)
                acc[mi][ni] = __builtin_amdgcn_mfma_f32_16x16x32_bf16(
                    afr[mi], bfr[ni], acc[mi][ni], 0, 0, 0);
    }

    #pragma unroll
    for (int mi = 0; mi < 4; ++mi) {
        int rbase = wm * 64 + mi * 16 + q * 4;
        #pragma unroll
        for (int r = 0; r < 4; ++r) {
            int row = rbase + r;
            int gi = ty * 128 + row;
            bool ok = gi < n_e;
            int v = rid_sh[row];
            float g = gt_sh[row];
            size_t orow = (size_t)(v >> 1) * D_OUT;
            #pragma unroll
            for (int ni = 0; ni < 4; ++ni) {
                int c = n0 + wn * 64 + ni * 16 + lm;
                float val = g * __expf(acc[mi][ni][r]);
                if (ok) {
                    if (USE_CONTRIB) {
                        float* dst = (v & 1) ? contrib : out;
                        dst[orow + c] = val;
                    } else {
                        atomicAdd(&out[orow + c], val);
                    }
                }
            }
        }
    }
}

// ---------------------------------------------------------------------------
// Combine: out = log(clamp(slot0 + slot1, eps))
// ---------------------------------------------------------------------------
__global__ __launch_bounds__(256) void combine_add_log(
        float* __restrict__ out, const float* __restrict__ contrib, int n4) {
    int i = blockIdx.x * blockDim.x + threadIdx.x;
    if (i >= n4) return;
    float4 a = ((const float4*)out)[i];
    float4 b = ((const float4*)contrib)[i];
    float4 r;
    float s;
    s = a.x + b.x; s = (s == 0.f) ? EPSF : s; r.x = __logf(s);
    s = a.y + b.y; s = (s == 0.f) ? EPSF : s; r.y = __logf(s);
    s = a.z + b.z; s = (s == 0.f) ? EPSF : s; r.z = __logf(s);
    s = a.w + b.w; s = (s == 0.f) ? EPSF : s; r.w = __logf(s);
    ((float4*)out)[i] = r;
}

__global__ __launch_bounds__(256) void log_inplace(float* __restrict__ out, int n4) {
    int i = blockIdx.x * blockDim.x + threadIdx.x;
    if (i >= n4) return;
    float4 a = ((float4*)out)[i];
    float4 r;
    float s;
    s = a.x; s = (s == 0.f) ? EPSF : s; r.x = __logf(s);
    s = a.y; s = (s == 0.f) ? EPSF : s; r.y = __logf(s);
    s = a.z; s = (s == 0.f) ? EPSF : s; r.z = __logf(s);
    s = a.w; s = (s == 0.f) ? EPSF : s; r.w = __logf(s);
    ((float4*)out)[i] = r;
}

extern "C" void kernel_launch(void* const* d_in, const int* in_sizes, int n_in,
                              void* d_out, int out_size, void* d_ws, size_t ws_size,
                              hipStream_t stream) {
    const float* x  = (const float*)d_in[0];
    const float* wr = (const float*)d_in[1];
    const float* we = (const float*)d_in[2];
    float* out = (float*)d_out;
    char* ws = (char*)d_ws;

    size_t off = 0;
    int*   counts  = (int*)(ws + off);   off += 1024;                 // 16 x 64B lines
    int*   rowlist = (int*)(ws + off);   off += (size_t)NEXP * B_ROWS * 4;
    float* gates   = (float*)(ws + off); off += (size_t)NEXP * B_ROWS * 4;
    float* wrT     = (float*)(ws + off); off += (size_t)NEXP * D_IN * 4;
    float* contrib = (float*)(ws + off); off += (size_t)B_ROWS * D_OUT * 4;
    size_t tier2_need = off;
    u16_t* xb      = (u16_t*)(ws + off); off += (size_t)B_ROWS * D_IN * 2;
    u16_t* wTb     = (u16_t*)(ws + off); off += (size_t)NEXP * D_IN * D_OUT * 2;
    size_t tier3_need = off;

    hipMemsetAsync(counts, 0, 1024, stream);
    transpose_wr<<<NEXP * D_IN / 256, 256, 0, stream>>>(wr, wrT);
    router_kernel<<<B_ROWS / 32, 256, 0, stream>>>(x, wrT, counts, rowlist, gates);

    dim3 g(D_OUT / 128, B_ROWS / 128, NEXP);
    int n4 = B_ROWS * D_OUT / 4;

    if (ws_size >= tier3_need) {
        convert_x<<<(B_ROWS * D_IN / 8) / 256, 256, 0, stream>>>(x, xb);
        dim3 gw(D_IN / 128, D_OUT / 64, NEXP);
        convert_wT<<<gw, 256, 0, stream>>>(we, wTb);
        moe_gemm_bf16<true><<<g, 256, 0, stream>>>(xb, wTb, counts, rowlist, gates, out, contrib);
        combine_add_log<<<(n4 + 255) / 256, 256, 0, stream>>>(out, contrib, n4);
    } else if (ws_size >= tier2_need) {
        moe_gemm<true><<<g, 256, 0, stream>>>(x, we, counts, rowlist, gates, out, contrib);
        combine_add_log<<<(n4 + 255) / 256, 256, 0, stream>>>(out, contrib, n4);
    } else {
        hipMemsetAsync(out, 0, (size_t)B_ROWS * D_OUT * 4, stream);
        moe_gemm<false><<<g, 256, 0, stream>>>(x, we, counts, rowlist, gates, out, nullptr);
        log_inplace<<<(n4 + 255) / 256, 256, 0, stream>>>(out, n4);
    }
}

// Round 5
// 279.409 us; speedup vs baseline: 1.0282x; 1.0282x over previous
//
#include <hip/hip_runtime.h>
#include <hip/hip_bf16.h>

typedef unsigned short u16_t;
typedef unsigned int   u32_t;

#define B_ROWS  16384
#define D_IN    1024
#define D_OUT   512
#define NEXP    16
#define CNT_STRIDE 16   // pad each expert counter to its own 64B line (R2 post-mortem)
#define EPSF    2.2204460492503131e-16f

using short8  = __attribute__((ext_vector_type(8))) short;
using floatx4 = __attribute__((ext_vector_type(4))) float;

__device__ __forceinline__ u16_t f2bf(float f) {
    u32_t u = __float_as_uint(f);
    u += 0x7fffu + ((u >> 16) & 1u);        // round-to-nearest-even
    return (u16_t)(u >> 16);
}

// ---------------------------------------------------------------------------
// Fused prep (R4 post-mortem: 8 dispatches -> launch gaps; fuse the 4 small
// ones). Work split by blockIdx.x:
//   [0, 8192)        x f32 -> bf16 row-major (8 elems/thread); block 0 also
//                    zeroes the padded counts array.
//   [8192, 9216)     w_experts [e][k][n] -> wT [e][n][k] bf16, LDS-tiled
//                    128k x 64n (coalesced both sides).
//   [9216, 9280)     w_router [D_IN][E] -> wrT [E][D_IN] f32.
// ---------------------------------------------------------------------------
__global__ __launch_bounds__(256) void prep_kernel(
        const float* __restrict__ x, const float* __restrict__ wr,
        const float* __restrict__ we,
        u16_t* __restrict__ xb, float* __restrict__ wrT,
        u16_t* __restrict__ wT, int* __restrict__ counts) {
    __shared__ u16_t sh[128][72];               // pad 64->72 (transpose tile)
    int blk = blockIdx.x;
    int t = threadIdx.x;
    if (blk < 8192) {
        if (blk == 0) counts[t] = 0;            // 256 ints = full padded array
        size_t i = ((size_t)blk * 256 + t) * 8;
        float4 a = *(const float4*)(x + i);
        float4 b = *(const float4*)(x + i + 4);
        union { u16_t us[8]; uint4 v; } p;
        p.us[0] = f2bf(a.x); p.us[1] = f2bf(a.y); p.us[2] = f2bf(a.z); p.us[3] = f2bf(a.w);
        p.us[4] = f2bf(b.x); p.us[5] = f2bf(b.y); p.us[6] = f2bf(b.z); p.us[7] = f2bf(b.w);
        *(uint4*)(xb + i) = p.v;
    } else if (blk < 9216) {
        int b = blk - 8192;
        int e = b >> 6, k0 = ((b >> 3) & 7) * 128, n0 = (b & 7) * 64;
        int kk = t >> 4, nc = (t & 15) * 4;
        const float* src = we + ((size_t)e * D_IN + k0 + kk) * D_OUT + n0 + nc;
        #pragma unroll
        for (int p = 0; p < 8; ++p) {
            float4 v = *(const float4*)(src + (size_t)p * 16 * D_OUT);
            sh[p * 16 + kk][nc + 0] = f2bf(v.x);
            sh[p * 16 + kk][nc + 1] = f2bf(v.y);
            sh[p * 16 + kk][nc + 2] = f2bf(v.z);
            sh[p * 16 + kk][nc + 3] = f2bf(v.w);
        }
        __syncthreads();
        int nn = t >> 2, c = t & 3;             // 4 threads per n-row, 64B each
        u16_t* dst = wT + ((size_t)e * D_OUT + n0 + nn) * D_IN + k0 + c * 32;
        #pragma unroll
        for (int j = 0; j < 4; ++j) {
            union { u16_t us[8]; uint4 v; } p;
            #pragma unroll
            for (int jj = 0; jj < 8; ++jj) p.us[jj] = sh[c * 32 + j * 8 + jj][nn];
            *(uint4*)(dst + j * 8) = p.v;
        }
    } else {
        int i = (blk - 9216) * 256 + t;         // i = e*D_IN + d
        int e = i >> 10, d = i & 1023;
        wrT[i] = wr[d * NEXP + e];
    }
}

// ---------------------------------------------------------------------------
// Router v4: 32 rows/block, thread=(row lr=t>>3, oct q=t&7), wrT in LDS.
// q-minor chunking d=i*32+q*4: 8 q-lanes span all 32 banks once ->
// conflict-free. f64 dots (exact top-2 vs np ref); hierarchical atomics.
// ---------------------------------------------------------------------------
__global__ __launch_bounds__(256) void router_kernel(
        const float* __restrict__ x, const float* __restrict__ wrT,
        int* __restrict__ counts, int* __restrict__ rowlist,
        float* __restrict__ gatelist) {
    __shared__ float wsh[NEXP * D_IN];          // 64 KB [e][d]
    __shared__ int hist[NEXP], base[NEXP], hist2[NEXP];
    __shared__ unsigned char eidx_sh[32][2];
    __shared__ float g_sh[32][2];

    int t = threadIdx.x;
    {   // stage wrT: 16384 floats / 256 threads = 16 float4 each
        const float4* src = (const float4*)wrT;
        float4* dst = (float4*)wsh;
        #pragma unroll
        for (int i = 0; i < 16; ++i) dst[t + 256 * i] = src[t + 256 * i];
    }
    if (t < NEXP) { hist[t] = 0; hist2[t] = 0; }
    __syncthreads();

    int lr = t >> 3, q = t & 7;
    int row = blockIdx.x * 32 + lr;
    const float4* xq = (const float4*)(x + (size_t)row * D_IN);

    double acc[NEXP];
    #pragma unroll
    for (int e = 0; e < NEXP; ++e) acc[e] = 0.0;

    for (int i = 0; i < 32; ++i) {
        float4 xv = xq[i * 8 + q];              // d = i*32 + q*4
        double x0 = xv.x, x1 = xv.y, x2 = xv.z, x3 = xv.w;
        #pragma unroll
        for (int e = 0; e < NEXP; ++e) {
            float4 wv = *(const float4*)(&wsh[e * D_IN + i * 32 + q * 4]);
            acc[e] += x0 * (double)wv.x;
            acc[e] += x1 * (double)wv.y;
            acc[e] += x2 * (double)wv.z;
            acc[e] += x3 * (double)wv.w;
        }
    }
    #pragma unroll
    for (int e = 0; e < NEXP; ++e) {
        acc[e] += __shfl_xor(acc[e], 1);
        acc[e] += __shfl_xor(acc[e], 2);
        acc[e] += __shfl_xor(acc[e], 4);
    }
    if (q == 0) {
        // top-2, stable (lower index wins ties) == jax.lax.top_k
        int i1 = 0; double v1 = acc[0];
        #pragma unroll
        for (int e = 1; e < NEXP; ++e) if (acc[e] > v1) { v1 = acc[e]; i1 = e; }
        int i2 = -1; double v2 = -1.0e300;
        #pragma unroll
        for (int e = 0; e < NEXP; ++e) if (e != i1 && acc[e] > v2) { v2 = acc[e]; i2 = e; }
        double ed = exp(v2 - v1);               // <= 1
        double s = 1.0 + ed;
        eidx_sh[lr][0] = (unsigned char)i1; g_sh[lr][0] = (float)(1.0 / s);
        eidx_sh[lr][1] = (unsigned char)i2; g_sh[lr][1] = (float)(ed / s);
        atomicAdd(&hist[i1], 1);
        atomicAdd(&hist[i2], 1);
    }
    __syncthreads();
    if (t < NEXP) base[t] = atomicAdd(&counts[t * CNT_STRIDE], hist[t]);
    __syncthreads();
    if (t < 64) {
        int r = t >> 1, sl = t & 1;
        int e = eidx_sh[r][sl];
        int pos = base[e] + atomicAdd(&hist2[e], 1);
        rowlist[e * B_ROWS + pos] = ((blockIdx.x * 32 + r) << 1) | sl;
        gatelist[e * B_ROWS + pos] = g_sh[r][sl];
    }
}

// ---------------------------------------------------------------------------
// Grouped expert GEMM v3 (R4 post-mortem: glds+vmcnt(0) barrier serialized
// the pipeline; LDS was 2x oversized). R3 dataflow (VGPR-staged loads issued
// before the first barrier -> latency overlaps other waves' compute) with
// R4's conflict-free fragment-order LDS layout [tile][q][lm] where the
// staging chunk id == threadIdx.x: ds_write_b128 and ds_read_b128 are both
// lane-linear (0 bank conflicts). Global side: one staging instr covers
// 16 rows x 64B full lines (coalesced). 128x128 tile, BK=32, 2x2 waves.
// ---------------------------------------------------------------------------
template<bool USE_CONTRIB>
__global__ __launch_bounds__(256) void moe_gemm_bf16(
        const u16_t* __restrict__ xb, const u16_t* __restrict__ wT,
        const int* __restrict__ counts, const int* __restrict__ rowlist,
        const float* __restrict__ gatelist,
        float* __restrict__ out, float* __restrict__ contrib) {
    int e = blockIdx.z;
    int n_e = counts[e * CNT_STRIDE];
    int ty = blockIdx.y;
    if (ty * 128 >= n_e) return;
    int n0 = blockIdx.x * 128;

    // [tile(8)][q(4)][lm(16)] 16B chunks = 4096 u16 = 8 KB each
    __shared__ __align__(16) u16_t Af[4096];
    __shared__ __align__(16) u16_t Bf[4096];
    __shared__ int   rid_sh[128];
    __shared__ float gt_sh[128];

    int t = threadIdx.x;
    if (t < 128) {
        int gi = ty * 128 + t;
        int v = 0; float g = 0.f;
        if (gi < n_e) { v = rowlist[e * B_ROWS + gi]; g = gatelist[e * B_ROWS + gi]; }
        rid_sh[t] = v; gt_sh[t] = g;
    }
    __syncthreads();

    // staging: chunk c0 = t (tile=t>>6, q=(t>>4)&3, lm=t&15), c1 = t+256.
    int s_lm = t & 15, s_q = (t >> 4) & 3, s_tile = t >> 6;
    int rowA0 = s_tile * 16 + s_lm, rowA1 = rowA0 + 64;
    const u16_t* aG0 = xb + (size_t)(rid_sh[rowA0] >> 1) * D_IN + s_q * 8;
    const u16_t* aG1 = xb + (size_t)(rid_sh[rowA1] >> 1) * D_IN + s_q * 8;
    const u16_t* bG0 = wT + ((size_t)e * D_OUT + n0 + rowA0) * D_IN + s_q * 8;
    const u16_t* bG1 = wT + ((size_t)e * D_OUT + n0 + rowA1) * D_IN + s_q * 8;
    u16_t* aL0 = Af + t * 8;          // lane-linear 16B chunks
    u16_t* aL1 = Af + (t + 256) * 8;
    u16_t* bL0 = Bf + t * 8;
    u16_t* bL1 = Bf + (t + 256) * 8;

    int lane = t & 63, wv = t >> 6;
    int wm = wv >> 1, wn = wv & 1;
    int lm = lane & 15, q = lane >> 4;

    floatx4 acc[4][4];
    #pragma unroll
    for (int mi = 0; mi < 4; ++mi)
        #pragma unroll
        for (int ni = 0; ni < 4; ++ni)
            acc[mi][ni] = (floatx4){0.f, 0.f, 0.f, 0.f};

    for (int it = 0; it < D_IN / 32; ++it) {
        uint4 a0 = *(const uint4*)aG0;      // issued before barrier: latency
        uint4 a1 = *(const uint4*)aG1;      // overlaps other waves' compute
        uint4 b0 = *(const uint4*)bG0;
        uint4 b1 = *(const uint4*)bG1;
        aG0 += 32; aG1 += 32; bG0 += 32; bG1 += 32;

        __syncthreads();                    // prev iter's fragment reads done
        *(uint4*)aL0 = a0;
        *(uint4*)aL1 = a1;
        *(uint4*)bL0 = b0;
        *(uint4*)bL1 = b1;
        __syncthreads();                    // tiles resident

        short8 afr[4], bfr[4];
        #pragma unroll
        for (int mi = 0; mi < 4; ++mi)
            afr[mi] = *(const short8*)(Af + ((wm * 4 + mi) * 64 + lane) * 8);
        #pragma unroll
        for (int ni = 0; ni < 4; ++ni)
            bfr[ni] = *(const short8*)(Bf + ((wn * 4 + ni) * 64 + lane) * 8);
        #pragma unroll
        for (int mi = 0; mi < 4; ++mi)
            #pragma unroll
            for (int ni = 0; ni < 4; ++ni)
                acc[mi][ni] = __builtin_amdgcn_mfma_f32_16x16x32_bf16(
                    afr[mi], bfr[ni], acc[mi][ni], 0, 0, 0);
    }

    // epilogue: C/D layout col=lane&15, row=(lane>>4)*4+reg
    #pragma unroll
    for (int mi = 0; mi < 4; ++mi) {
        int rbase = wm * 64 + mi * 16 + q * 4;
        #pragma unroll
        for (int r = 0; r < 4; ++r) {
            int row = rbase + r;
            int gi = ty * 128 + row;
            bool ok = gi < n_e;
            int v = rid_sh[row];
            float g = gt_sh[row];
            size_t orow = (size_t)(v >> 1) * D_OUT;
            #pragma unroll
            for (int ni = 0; ni < 4; ++ni) {
                int c = n0 + wn * 64 + ni * 16 + lm;
                float val = g * __expf(acc[mi][ni][r]);
                if (ok) {
                    if (USE_CONTRIB) {
                        float* dst = (v & 1) ? contrib : out;
                        dst[orow + c] = val;
                    } else {
                        atomicAdd(&out[orow + c], val);
                    }
                }
            }
        }
    }
}

// ---------------------------------------------------------------------------
// Fallback f32-input GEMM (used only when ws too small for bf16 buffers).
// ---------------------------------------------------------------------------
template<bool USE_CONTRIB>
__global__ __launch_bounds__(256) void moe_gemm(
        const float* __restrict__ x, const float* __restrict__ w,
        const int* __restrict__ counts, const int* __restrict__ rowlist,
        const float* __restrict__ gatelist,
        float* __restrict__ out, float* __restrict__ contrib) {
    int e = blockIdx.z;
    int n_e = counts[e * CNT_STRIDE];
    int ty = blockIdx.y;
    if (ty * 128 >= n_e) return;
    int n0 = blockIdx.x * 128;

    __shared__ u16_t Ash[128][40];
    __shared__ u32_t Bsh[16][132];
    __shared__ int   rid_sh[128];
    __shared__ float gt_sh[128];

    int t = threadIdx.x;
    if (t < 128) {
        int gi = ty * 128 + t;
        int v = 0; float g = 0.f;
        if (gi < n_e) { v = rowlist[e * B_ROWS + gi]; g = gatelist[e * B_ROWS + gi]; }
        rid_sh[t] = v; gt_sh[t] = g;
    }
    __syncthreads();

    int ar = t >> 1, ah = t & 1;
    const float* xptr = x + (size_t)(rid_sh[ar] >> 1) * D_IN + ah * 16;
    int bkp = t >> 4, bng = t & 15;
    const float* wptr = w + (size_t)e * (D_IN * D_OUT)
                          + (size_t)(2 * bkp) * D_OUT + n0 + bng * 8;

    int lane = t & 63, wv = t >> 6;
    int wm = wv >> 1, wn = wv & 1;
    int lm = lane & 15, q = lane >> 4;

    floatx4 acc[4][4];
    #pragma unroll
    for (int mi = 0; mi < 4; ++mi)
        #pragma unroll
        for (int ni = 0; ni < 4; ++ni)
            acc[mi][ni] = (floatx4){0.f, 0.f, 0.f, 0.f};

    for (int it = 0; it < D_IN / 32; ++it) {
        float4 av0 = *(const float4*)(xptr + 0);
        float4 av1 = *(const float4*)(xptr + 4);
        float4 av2 = *(const float4*)(xptr + 8);
        float4 av3 = *(const float4*)(xptr + 12);
        xptr += 32;
        float4 b0 = *(const float4*)(wptr + 0);
        float4 b1 = *(const float4*)(wptr + 4);
        float4 b2 = *(const float4*)(wptr + D_OUT);
        float4 b3 = *(const float4*)(wptr + D_OUT + 4);
        wptr += 32 * D_OUT;

        __syncthreads();
        {
            union { u16_t us[16]; uint4 v[2]; } ap;
            float af[16] = {av0.x, av0.y, av0.z, av0.w, av1.x, av1.y, av1.z, av1.w,
                            av2.x, av2.y, av2.z, av2.w, av3.x, av3.y, av3.z, av3.w};
            #pragma unroll
            for (int j = 0; j < 16; ++j) ap.us[j] = f2bf(af[j]);
            *(uint4*)(&Ash[ar][ah * 16])     = ap.v[0];
            *(uint4*)(&Ash[ar][ah * 16 + 8]) = ap.v[1];
        }
        {
            union { u32_t up[8]; uint4 v[2]; } bp;
            bp.up[0] = (u32_t)f2bf(b0.x) | ((u32_t)f2bf(b2.x) << 16);
            bp.up[1] = (u32_t)f2bf(b0.y) | ((u32_t)f2bf(b2.y) << 16);
            bp.up[2] = (u32_t)f2bf(b0.z) | ((u32_t)f2bf(b2.z) << 16);
            bp.up[3] = (u32_t)f2bf(b0.w) | ((u32_t)f2bf(b2.w) << 16);
            bp.up[4] = (u32_t)f2bf(b1.x) | ((u32_t)f2bf(b3.x) << 16);
            bp.up[5] = (u32_t)f2bf(b1.y) | ((u32_t)f2bf(b3.y) << 16);
            bp.up[6] = (u32_t)f2bf(b1.z) | ((u32_t)f2bf(b3.z) << 16);
            bp.up[7] = (u32_t)f2bf(b1.w) | ((u32_t)f2bf(b3.w) << 16);
            *(uint4*)(&Bsh[bkp][bng * 8])     = bp.v[0];
            *(uint4*)(&Bsh[bkp][bng * 8 + 4]) = bp.v[1];
        }
        __syncthreads();

        short8 afr[4];
        #pragma unroll
        for (int mi = 0; mi < 4; ++mi)
            afr[mi] = *(const short8*)(&Ash[wm * 64 + mi * 16 + lm][q * 8]);
        short8 bfr[4];
        #pragma unroll
        for (int ni = 0; ni < 4; ++ni) {
            int nn = wn * 64 + ni * 16 + lm;
            union { uint4 u; short8 s; } cv;
            cv.u.x = Bsh[q * 4 + 0][nn];
            cv.u.y = Bsh[q * 4 + 1][nn];
            cv.u.z = Bsh[q * 4 + 2][nn];
            cv.u.w = Bsh[q * 4 + 3][nn];
            bfr[ni] = cv.s;
        }
        #pragma unroll
        for (int mi = 0; mi < 4; ++mi)
            #pragma unroll
            for (int ni = 0; ni < 4; ++ni)
                acc[mi][ni] = __builtin_amdgcn_mfma_f32_16x16x32_bf16(
                    afr[mi], bfr[ni], acc[mi][ni], 0, 0, 0);
    }

    #pragma unroll
    for (int mi = 0; mi < 4; ++mi) {
        int rbase = wm * 64 + mi * 16 + q * 4;
        #pragma unroll
        for (int r = 0; r < 4; ++r) {
            int row = rbase + r;
            int gi = ty * 128 + row;
            bool ok = gi < n_e;
            int v = rid_sh[row];
            float g = gt_sh[row];
            size_t orow = (size_t)(v >> 1) * D_OUT;
            #pragma unroll
            for (int ni = 0; ni < 4; ++ni) {
                int c = n0 + wn * 64 + ni * 16 + lm;
                float val = g * __expf(acc[mi][ni][r]);
                if (ok) {
                    if (USE_CONTRIB) {
                        float* dst = (v & 1) ? contrib : out;
                        dst[orow + c] = val;
                    } else {
                        atomicAdd(&out[orow + c], val);
                    }
                }
            }
        }
    }
}

// ---------------------------------------------------------------------------
// Combine: out = log(clamp(slot0 + slot1, eps))
// ---------------------------------------------------------------------------
__global__ __launch_bounds__(256) void combine_add_log(
        float* __restrict__ out, const float* __restrict__ contrib, int n4) {
    int i = blockIdx.x * blockDim.x + threadIdx.x;
    if (i >= n4) return;
    float4 a = ((const float4*)out)[i];
    float4 b = ((const float4*)contrib)[i];
    float4 r;
    float s;
    s = a.x + b.x; s = (s == 0.f) ? EPSF : s; r.x = __logf(s);
    s = a.y + b.y; s = (s == 0.f) ? EPSF : s; r.y = __logf(s);
    s = a.z + b.z; s = (s == 0.f) ? EPSF : s; r.z = __logf(s);
    s = a.w + b.w; s = (s == 0.f) ? EPSF : s; r.w = __logf(s);
    ((float4*)out)[i] = r;
}

__global__ __launch_bounds__(256) void log_inplace(float* __restrict__ out, int n4) {
    int i = blockIdx.x * blockDim.x + threadIdx.x;
    if (i >= n4) return;
    float4 a = ((float4*)out)[i];
    float4 r;
    float s;
    s = a.x; s = (s == 0.f) ? EPSF : s; r.x = __logf(s);
    s = a.y; s = (s == 0.f) ? EPSF : s; r.y = __logf(s);
    s = a.z; s = (s == 0.f) ? EPSF : s; r.z = __logf(s);
    s = a.w; s = (s == 0.f) ? EPSF : s; r.w = __logf(s);
    ((float4*)out)[i] = r;
}

extern "C" void kernel_launch(void* const* d_in, const int* in_sizes, int n_in,
                              void* d_out, int out_size, void* d_ws, size_t ws_size,
                              hipStream_t stream) {
    const float* x  = (const float*)d_in[0];
    const float* wr = (const float*)d_in[1];
    const float* we = (const float*)d_in[2];
    float* out = (float*)d_out;
    char* ws = (char*)d_ws;

    size_t off = 0;
    int*   counts  = (int*)(ws + off);   off += 1024;                 // 16 x 64B lines
    int*   rowlist = (int*)(ws + off);   off += (size_t)NEXP * B_ROWS * 4;
    float* gates   = (float*)(ws + off); off += (size_t)NEXP * B_ROWS * 4;
    float* wrT     = (float*)(ws + off); off += (size_t)NEXP * D_IN * 4;
    float* contrib = (float*)(ws + off); off += (size_t)B_ROWS * D_OUT * 4;
    size_t tier2_need = off;
    u16_t* xb      = (u16_t*)(ws + off); off += (size_t)B_ROWS * D_IN * 2;
    u16_t* wTb     = (u16_t*)(ws + off); off += (size_t)NEXP * D_IN * D_OUT * 2;
    size_t tier3_need = off;

    dim3 g(D_OUT / 128, B_ROWS / 128, NEXP);
    int n4 = B_ROWS * D_OUT / 4;

    if (ws_size >= tier3_need) {
        prep_kernel<<<9280, 256, 0, stream>>>(x, wr, we, xb, wrT, wTb, counts);
        router_kernel<<<B_ROWS / 32, 256, 0, stream>>>(x, wrT, counts, rowlist, gates);
        moe_gemm_bf16<true><<<g, 256, 0, stream>>>(xb, wTb, counts, rowlist, gates, out, contrib);
        combine_add_log<<<(n4 + 255) / 256, 256, 0, stream>>>(out, contrib, n4);
    } else if (ws_size >= tier2_need) {
        hipMemsetAsync(counts, 0, 1024, stream);
        transpose_wr_dummy: ;
        {
            // reuse prep for wrT only is not possible below tier3 (needs xb/wTb),
            // so do the small transpose inline via a dedicated launch of prep's
            // tail range is not available; fall back to a tiny kernel-free path:
        }
        // tier2: router needs wrT; emulate with a small grid of prep's tail.
        // Simplest: dedicated transpose kernel retained below.
        extern __global__ void transpose_wr_k(const float*, float*);
        transpose_wr_k<<<NEXP * D_IN / 256, 256, 0, stream>>>(wr, wrT);
        router_kernel<<<B_ROWS / 32, 256, 0, stream>>>(x, wrT, counts, rowlist, gates);
        moe_gemm<true><<<g, 256, 0, stream>>>(x, we, counts, rowlist, gates, out, contrib);
        combine_add_log<<<(n4 + 255) / 256, 256, 0, stream>>>(out, contrib, n4);
    } else {
        hipMemsetAsync(counts, 0, 1024, stream);
        extern __global__ void transpose_wr_k(const float*, float*);
        transpose_wr_k<<<NEXP * D_IN / 256, 256, 0, stream>>>(wr, wrT);
        router_kernel<<<B_ROWS / 32, 256, 0, stream>>>(x, wrT, counts, rowlist, gates);
        hipMemsetAsync(out, 0, (size_t)B_ROWS * D_OUT * 4, stream);
        moe_gemm<false><<<g, 256, 0, stream>>>(x, we, counts, rowlist, gates, out, nullptr);
        log_inplace<<<(n4 + 255) / 256, 256, 0, stream>>>(out, n4);
    }
}

// small transpose used only by fallback tiers
__global__ __launch_bounds__(256) void transpose_wr_k(
        const float* __restrict__ wr, float* __restrict__ wrT) {
    int i = blockIdx.x * 256 + threadIdx.x;
    int e = i >> 10, d = i & 1023;
    wrT[i] = wr[d * NEXP + e];
}